// Round 1
// baseline (174.477 us; speedup 1.0000x reference)
//
#include <hip/hip_runtime.h>

// RoI crop_and_resize (tf.image.crop_and_resize, bilinear), single image.
// feature: [1,50,50,1024] f32; rois: [512,4] f32 (y1,x1,y2,x2 in pixels);
// img_size: [2] i32 (=800,800). Output: [512,14,14,1024] f32.

#define FH 50
#define FW 50
#define FC 1024
#define PH 14
#define PW 14

__global__ __launch_bounds__(256) void roi_crop_resize_kernel(
    const float* __restrict__ feat,
    const float* __restrict__ rois,
    const int* __restrict__ img_size,
    float* __restrict__ out,
    int n_cells)  // n_rois * PH * PW
{
    int cell = blockIdx.x;
    if (cell >= n_cells) return;

    int n  = cell / (PH * PW);
    int ij = cell - n * (PH * PW);
    int i  = ij / PW;
    int j  = ij - i * PW;

    float hs = (float)img_size[0];
    float ws = (float)img_size[1];

    // normalized box
    float by1 = rois[n * 4 + 0] / hs;
    float bx1 = rois[n * 4 + 1] / ws;
    float by2 = rois[n * 4 + 2] / hs;
    float bx2 = rois[n * 4 + 3] / ws;

    float ty = (float)i / (float)(PH - 1);
    float tx = (float)j / (float)(PW - 1);

    float ys = (by1 + ty * (by2 - by1)) * (float)(FH - 1);
    float xs = (bx1 + tx * (bx2 - bx1)) * (float)(FW - 1);

    float y0f = floorf(ys);
    float x0f = floorf(xs);
    float wy = ys - y0f;
    float wx = xs - x0f;

    int y0  = (int)fminf(fmaxf(y0f,        0.0f), (float)(FH - 1));
    int y1i = (int)fminf(fmaxf(y0f + 1.0f, 0.0f), (float)(FH - 1));
    int x0  = (int)fminf(fmaxf(x0f,        0.0f), (float)(FW - 1));
    int x1i = (int)fminf(fmaxf(x0f + 1.0f, 0.0f), (float)(FW - 1));

    const float4* r00 = (const float4*)(feat + ((size_t)(y0  * FW + x0 ) * FC));
    const float4* r01 = (const float4*)(feat + ((size_t)(y0  * FW + x1i) * FC));
    const float4* r10 = (const float4*)(feat + ((size_t)(y1i * FW + x0 ) * FC));
    const float4* r11 = (const float4*)(feat + ((size_t)(y1i * FW + x1i) * FC));
    float4* o = (float4*)(out + (size_t)cell * FC);

    int t = threadIdx.x;  // 0..255, FC/4 = 256 float4s per cell

    float4 a = r00[t];
    float4 b = r01[t];
    float4 c = r10[t];
    float4 d = r11[t];

    float omwx = 1.0f - wx;
    float omwy = 1.0f - wy;

    // match reference ordering: top = a*(1-wx)+b*wx; bot = c*(1-wx)+d*wx;
    // out = top*(1-wy) + bot*wy
    float4 res;
    res.x = (a.x * omwx + b.x * wx) * omwy + (c.x * omwx + d.x * wx) * wy;
    res.y = (a.y * omwx + b.y * wx) * omwy + (c.y * omwx + d.y * wx) * wy;
    res.z = (a.z * omwx + b.z * wx) * omwy + (c.z * omwx + d.z * wx) * wy;
    res.w = (a.w * omwx + b.w * wx) * omwy + (c.w * omwx + d.w * wx) * wy;

    o[t] = res;
}

extern "C" void kernel_launch(void* const* d_in, const int* in_sizes, int n_in,
                              void* d_out, int out_size, void* d_ws, size_t ws_size,
                              hipStream_t stream) {
    const float* feat     = (const float*)d_in[0];
    const float* rois     = (const float*)d_in[1];
    const int*   img_size = (const int*)d_in[2];
    float* out = (float*)d_out;

    int n_rois  = in_sizes[1] / 4;           // 512
    int n_cells = n_rois * PH * PW;          // 100352

    roi_crop_resize_kernel<<<n_cells, 256, 0, stream>>>(
        feat, rois, img_size, out, n_cells);
}

// Round 3
// 114.940 us; speedup vs baseline: 1.5180x; 1.5180x over previous
//
#include <hip/hip_runtime.h>

// RoI crop_and_resize (tf.image.crop_and_resize, bilinear), single image.
// feature: [1,50,50,1024] f32; rois: [512,4] f32 (y1,x1,y2,x2 in pixels);
// img_size: [2] i32 (=800,800). Output: [512,14,14,1024] f32.
//
// R2: same as R1 but with a native ext_vector float4 so
// __builtin_nontemporal_store/load compile (HIP's float4 class is rejected).

#define FH 50
#define FW 50
#define FC 1024
#define PH 14
#define PW 14
#define NXCD 8

typedef float f32x4 __attribute__((ext_vector_type(4)));

__global__ __launch_bounds__(256) void roi_crop_resize_kernel(
    const float* __restrict__ feat,
    const float* __restrict__ rois,
    const int* __restrict__ img_size,
    float* __restrict__ out,
    int n_cells)  // n_rois * PH * PW, divisible by 8 here (100352)
{
    // ---- XCD swizzle: hardware round-robins blockIdx across 8 XCDs.
    // We want cell (n, ij) to run on XCD (n % 8), with each RoI's 196
    // cells contiguous in that XCD's dispatch order.
    int bid  = blockIdx.x;
    int xcd  = bid & (NXCD - 1);
    int slot = bid >> 3;                 // n_cells/8 slots per XCD
    int n    = (slot / (PH * PW)) * NXCD + xcd;
    int ij   = slot - (slot / (PH * PW)) * (PH * PW);
    int cell = n * (PH * PW) + ij;
    if (cell >= n_cells) return;

    int i = ij / PW;
    int j = ij - i * PW;

    float hs = (float)img_size[0];
    float ws = (float)img_size[1];

    // normalized box
    float by1 = rois[n * 4 + 0] / hs;
    float bx1 = rois[n * 4 + 1] / ws;
    float by2 = rois[n * 4 + 2] / hs;
    float bx2 = rois[n * 4 + 3] / ws;

    float ty = (float)i / (float)(PH - 1);
    float tx = (float)j / (float)(PW - 1);

    float ys = (by1 + ty * (by2 - by1)) * (float)(FH - 1);
    float xs = (bx1 + tx * (bx2 - bx1)) * (float)(FW - 1);

    float y0f = floorf(ys);
    float x0f = floorf(xs);
    float wy = ys - y0f;
    float wx = xs - x0f;

    int y0  = (int)fminf(fmaxf(y0f,        0.0f), (float)(FH - 1));
    int y1i = (int)fminf(fmaxf(y0f + 1.0f, 0.0f), (float)(FH - 1));
    int x0  = (int)fminf(fmaxf(x0f,        0.0f), (float)(FW - 1));
    int x1i = (int)fminf(fmaxf(x0f + 1.0f, 0.0f), (float)(FW - 1));

    const f32x4* r00 = (const f32x4*)(feat + ((size_t)(y0  * FW + x0 ) * FC));
    const f32x4* r01 = (const f32x4*)(feat + ((size_t)(y0  * FW + x1i) * FC));
    const f32x4* r10 = (const f32x4*)(feat + ((size_t)(y1i * FW + x0 ) * FC));
    const f32x4* r11 = (const f32x4*)(feat + ((size_t)(y1i * FW + x1i) * FC));
    f32x4* o = (f32x4*)(out + (size_t)cell * FC);

    int t = threadIdx.x;  // 0..255, FC/4 = 256 float4s per cell

    f32x4 a = r00[t];
    f32x4 b = r01[t];
    f32x4 c = r10[t];
    f32x4 d = r11[t];

    float omwx = 1.0f - wx;
    float omwy = 1.0f - wy;

    // match reference ordering: top = a*(1-wx)+b*wx; bot = c*(1-wx)+d*wx;
    // out = top*(1-wy) + bot*wy
    f32x4 res = (a * omwx + b * wx) * omwy + (c * omwx + d * wx) * wy;

    __builtin_nontemporal_store(res, &o[t]);
}

extern "C" void kernel_launch(void* const* d_in, const int* in_sizes, int n_in,
                              void* d_out, int out_size, void* d_ws, size_t ws_size,
                              hipStream_t stream) {
    const float* feat     = (const float*)d_in[0];
    const float* rois     = (const float*)d_in[1];
    const int*   img_size = (const int*)d_in[2];
    float* out = (float*)d_out;

    int n_rois  = in_sizes[1] / 4;           // 512
    int n_cells = n_rois * PH * PW;          // 100352

    roi_crop_resize_kernel<<<n_cells, 256, 0, stream>>>(
        feat, rois, img_size, out, n_cells);
}

// Round 4
// 108.999 us; speedup vs baseline: 1.6007x; 1.0545x over previous
//
#include <hip/hip_runtime.h>

// RoI crop_and_resize (tf.image.crop_and_resize, bilinear), single image.
// feature: [1,50,50,1024] f32; rois: [512,4] f32 (y1,x1,y2,x2 in pixels);
// img_size: [2] i32 (=800,800). Output: [512,14,14,1024] f32.
//
// R3: one block per output ROW (n,i) instead of per cell. 7168 blocks x 256
// threads, j-loop of 14. L1 captures the overlapping bilinear columns across
// adjacent j (sample spacing ~1.26px -> ~1.65x read reuse), RoI math and
// block preamble amortized 14x, 56 independent loads of ILP per thread.
// Keeps: XCD swizzle (RoI n -> XCD n%8) + nontemporal output stores.

#define FH 50
#define FW 50
#define FC 1024
#define PH 14
#define PW 14
#define NXCD 8

typedef float f32x4 __attribute__((ext_vector_type(4)));

__global__ __launch_bounds__(256) void roi_crop_resize_kernel(
    const float* __restrict__ feat,
    const float* __restrict__ rois,
    const int* __restrict__ img_size,
    float* __restrict__ out,
    int n_rows)  // n_rois * PH
{
    // XCD swizzle: hardware round-robins blockIdx across 8 XCDs.
    // Rows of RoI n run on XCD n%8; rows of one RoI are consecutive slots.
    int bid  = blockIdx.x;
    int xcd  = bid & (NXCD - 1);
    int slot = bid >> 3;                  // n_rows/8 slots per XCD
    int nroi = (slot / PH) * NXCD + xcd;
    int i    = slot - (slot / PH) * PH;
    if (nroi * PH + i >= n_rows) return;

    float hs = (float)img_size[0];
    float ws = (float)img_size[1];

    float by1 = rois[nroi * 4 + 0] / hs;
    float bx1 = rois[nroi * 4 + 1] / ws;
    float by2 = rois[nroi * 4 + 2] / hs;
    float bx2 = rois[nroi * 4 + 3] / ws;

    // y interpolation (fixed for the whole row)
    float ty  = (float)i * (1.0f / (float)(PH - 1));
    float ys  = (by1 + ty * (by2 - by1)) * (float)(FH - 1);
    float y0f = floorf(ys);
    float wy  = ys - y0f;
    int y0  = (int)fminf(fmaxf(y0f,        0.0f), (float)(FH - 1));
    int y1i = (int)fminf(fmaxf(y0f + 1.0f, 0.0f), (float)(FH - 1));

    const float* rowT = feat + (size_t)y0  * FW * FC;
    const float* rowB = feat + (size_t)y1i * FW * FC;
    float* orow = out + (size_t)(nroi * PH * PW + i * PW) * FC;

    int t = threadIdx.x;  // 0..255 -> channel quad
    float omwy = 1.0f - wy;
    float xscale = (bx2 - bx1) * (float)(FW - 1);
    float xbase  = bx1 * (float)(FW - 1);

    #pragma unroll
    for (int j = 0; j < PW; ++j) {
        float tx  = (float)j * (1.0f / (float)(PW - 1));
        float xs  = xbase + tx * xscale;
        float x0f = floorf(xs);
        float wx  = xs - x0f;
        int x0  = (int)fminf(fmaxf(x0f,        0.0f), (float)(FW - 1));
        int x1i = (int)fminf(fmaxf(x0f + 1.0f, 0.0f), (float)(FW - 1));

        f32x4 a = ((const f32x4*)(rowT + (size_t)x0  * FC))[t];
        f32x4 b = ((const f32x4*)(rowT + (size_t)x1i * FC))[t];
        f32x4 c = ((const f32x4*)(rowB + (size_t)x0  * FC))[t];
        f32x4 d = ((const f32x4*)(rowB + (size_t)x1i * FC))[t];

        float omwx = 1.0f - wx;
        // reference ordering: top*(1-wy) + bot*wy
        f32x4 res = (a * omwx + b * wx) * omwy + (c * omwx + d * wx) * wy;

        __builtin_nontemporal_store(res, (f32x4*)(orow + (size_t)j * FC) + t);
    }
}

extern "C" void kernel_launch(void* const* d_in, const int* in_sizes, int n_in,
                              void* d_out, int out_size, void* d_ws, size_t ws_size,
                              hipStream_t stream) {
    const float* feat     = (const float*)d_in[0];
    const float* rois     = (const float*)d_in[1];
    const int*   img_size = (const int*)d_in[2];
    float* out = (float*)d_out;

    int n_rois = in_sizes[1] / 4;        // 512
    int n_rows = n_rois * PH;            // 7168

    roi_crop_resize_kernel<<<n_rows, 256, 0, stream>>>(
        feat, rois, img_size, out, n_rows);
}

// Round 5
// 85.367 us; speedup vs baseline: 2.0438x; 1.2768x over previous
//
#include <hip/hip_runtime.h>

// RoI crop_and_resize (tf.image.crop_and_resize, bilinear), single image.
// feature: [1,50,50,1024] f32; rois: [512,4] f32; img_size: [2] i32.
// Output: [512,14,14,1024] f32.
//
// R4: block = (RoI n, 64-channel slice s). bid = 16n + s, so under round-robin
// XCD dispatch slice s always runs on XCD s&7 -> each XCD reads only 2/16 of
// the channel dim = 1.28 MB of feature, fully L2-resident -> cross-RoI
// re-reads become L2 hits. Inside a block, a rolling 2-row LDS ring (dynamic
// x-range of the box, 27 KB) captures all i->i+1 / j->j+1 reuse, so each
// block's global reads = its unique footprint slice, read once.
// Keeps nontemporal stores for the 411 MB streaming output.

#define FH 50
#define FW 50
#define FC 1024
#define PH 14
#define PW 14
#define CS 64                 // channels per slice
#define NSL (FC / CS)         // 16 slices
#define QS (CS / 4)           // 16 f32x4 quads per slice
#define COLPAD 17             // quads per column slot (16 + 1 pad -> bank rotate)

typedef float f32x4 __attribute__((ext_vector_type(4)));

__global__ __launch_bounds__(256) void roi_crop_resize_kernel(
    const float* __restrict__ feat,
    const float* __restrict__ rois,
    const int* __restrict__ img_size,
    float* __restrict__ out)
{
    __shared__ f32x4 lds[2][FW][COLPAD];   // 2*50*17*16B = 27,200 B

    int bid = blockIdx.x;
    int n = bid >> 4;          // RoI index
    int s = bid & (NSL - 1);   // channel slice
    int t = threadIdx.x;

    float hs = (float)img_size[0];
    float ws = (float)img_size[1];
    float by1 = rois[n * 4 + 0] / hs;
    float bx1 = rois[n * 4 + 1] / ws;
    float by2 = rois[n * 4 + 2] / hs;
    float bx2 = rois[n * 4 + 3] / ws;

    float ybase = by1 * (float)(FH - 1);
    float dy    = (by2 - by1) * (float)(FH - 1) * (1.0f / (float)(PH - 1));
    float xbase = bx1 * (float)(FW - 1);
    float dxs   = (bx2 - bx1) * (float)(FW - 1) * (1.0f / (float)(PW - 1));

    // x-range of this box (xs is always in [0, FW-1] since rois <= img_size)
    int xlo  = (int)floorf(xbase);
    int xhi  = min((int)floorf(xbase + (float)(PW - 1) * dxs) + 1, FW - 1);
    int ncol = xhi - xlo + 1;

    // compute-phase mapping: 16 lanes per output cell (64 ch), 16 j-groups (14 used)
    int q = t & 15;
    int j = t >> 4;
    float wx = 0.0f; int c0l = 0, c1l = 0;
    if (j < PW) {
        float xs  = xbase + (float)j * dxs;
        float x0f = floorf(xs);
        wx = xs - x0f;
        int x0 = (int)x0f;
        int x1 = min(x0 + 1, FW - 1);
        c0l = x0 - xlo;
        c1l = x1 - xlo;
    }

    const f32x4* featq = (const f32x4*)feat;
    int sq = s * QS;           // quad offset of this slice within a pixel (256 quads/pixel)

    int Lst = -1000;           // last feature row staged into the ring

    for (int i = 0; i < PH; ++i) {
        float ysf = ybase + (float)i * dy;
        float y0f = floorf(ysf);
        float wy  = ysf - y0f;
        int r0 = (int)y0f;
        int r1 = min(r0 + 1, FH - 1);

        // stage any rows not yet in the ring (r -> slot r&1; rows monotone non-decreasing,
        // so the last two staged rows are always exactly {r0, r1})
        int start = max(Lst + 1, r0);
        if (start <= r1) {
            __syncthreads();   // WAR: previous iteration's reads complete before overwrite
            for (int r = start; r <= r1; ++r) {
                f32x4* dst = &lds[r & 1][0][0];
                int base = (r * FW + xlo) * (FC / 4) + sq;
                for (int e = t; e < ncol * QS; e += 256) {
                    int col = e >> 4;
                    int qq  = e & 15;
                    dst[col * COLPAD + qq] = featq[base + col * (FC / 4) + qq];
                }
            }
            Lst = r1;
            __syncthreads();
        }

        if (j < PW) {
            const f32x4* rT = &lds[r0 & 1][0][0];
            const f32x4* rB = &lds[r1 & 1][0][0];
            f32x4 a = rT[c0l * COLPAD + q];
            f32x4 b = rT[c1l * COLPAD + q];
            f32x4 c = rB[c0l * COLPAD + q];
            f32x4 d = rB[c1l * COLPAD + q];
            float omwx = 1.0f - wx;
            float omwy = 1.0f - wy;
            // reference ordering: top = a*(1-wx)+b*wx; bot = c*(1-wx)+d*wx
            f32x4 res = (a * omwx + b * wx) * omwy + (c * omwx + d * wx) * wy;
            f32x4* o = (f32x4*)out + ((n * (PH * PW) + i * PW + j) * (FC / 4) + sq + q);
            __builtin_nontemporal_store(res, o);
        }
    }
}

extern "C" void kernel_launch(void* const* d_in, const int* in_sizes, int n_in,
                              void* d_out, int out_size, void* d_ws, size_t ws_size,
                              hipStream_t stream) {
    const float* feat     = (const float*)d_in[0];
    const float* rois     = (const float*)d_in[1];
    const int*   img_size = (const int*)d_in[2];
    float* out = (float*)d_out;

    int n_rois = in_sizes[1] / 4;            // 512
    int grid   = n_rois * NSL;               // 8192 blocks

    roi_crop_resize_kernel<<<grid, 256, 0, stream>>>(feat, rois, img_size, out);
}

// Round 6
// 80.712 us; speedup vs baseline: 2.1617x; 1.0577x over previous
//
#include <hip/hip_runtime.h>

// RoI crop_and_resize (tf.image.crop_and_resize, bilinear), single image.
// feature: [1,50,50,1024] f32; rois: [512,4] f32; img_size: [2] i32.
// Output: [512,14,14,1024] f32.
//
// R5: block = (RoI n, 64-channel slice s), bid = 16n + s -> slice s runs on
// XCD s&7 (round-robin dispatch), so each XCD reads only 2/16 channel slices
// = 1.28 MB of feature, fully L2-resident. NO LDS: with a 64-ch slice the
// active row-pair window is ~10 KB -> L1-resident, so direct global loads
// capture the bilinear reuse without barriers, staging instructions, or the
// LDS round-trip. Nontemporal stores keep the 411 MB streaming output out
// of the caches.

#define FH 50
#define FW 50
#define FC 1024
#define PH 14
#define PW 14
#define CS 64                 // channels per slice
#define NSL (FC / CS)         // 16 slices
#define QS (CS / 4)           // 16 f32x4 quads per slice

typedef float f32x4 __attribute__((ext_vector_type(4)));

__global__ __launch_bounds__(256) void roi_crop_resize_kernel(
    const float* __restrict__ feat,
    const float* __restrict__ rois,
    const int* __restrict__ img_size,
    float* __restrict__ out)
{
    int bid = blockIdx.x;
    int n = bid >> 4;          // RoI index
    int s = bid & (NSL - 1);   // channel slice -> XCD s&7
    int t = threadIdx.x;
    int q = t & 15;            // quad within slice (16 x f32x4 = 64 ch)
    int j = t >> 4;            // 0..15; j<14 active for compute

    float hs = (float)img_size[0];
    float ws = (float)img_size[1];
    float by1 = rois[n * 4 + 0] / hs;
    float bx1 = rois[n * 4 + 1] / ws;
    float by2 = rois[n * 4 + 2] / hs;
    float bx2 = rois[n * 4 + 3] / ws;

    float ybase = by1 * (float)(FH - 1);
    float dy    = (by2 - by1) * (float)(FH - 1) * (1.0f / (float)(PH - 1));
    float xbase = bx1 * (float)(FW - 1);
    float dxs   = (bx2 - bx1) * (float)(FW - 1) * (1.0f / (float)(PW - 1));

    // per-lane x interpolation (clamped so inactive lanes form valid addrs)
    float xs  = xbase + (float)j * dxs;
    float x0f = floorf(xs);
    float wx  = xs - x0f;
    int x0 = (int)fminf(fmaxf(x0f,        0.0f), (float)(FW - 1));
    int x1 = (int)fminf(fmaxf(x0f + 1.0f, 0.0f), (float)(FW - 1));
    float omwx = 1.0f - wx;

    const f32x4* fq = (const f32x4*)feat;
    int sq = s * QS + q;                       // quad index within a pixel
    f32x4* ob = (f32x4*)out + ((size_t)n * (PH * PW)) * (FC / 4) + sq;

    bool active = (j < PW);

    #pragma unroll
    for (int i = 0; i < PH; ++i) {
        float ysf = ybase + (float)i * dy;
        float y0f = floorf(ysf);
        float wy  = ysf - y0f;
        int r0 = (int)fminf(fmaxf(y0f,        0.0f), (float)(FH - 1));
        int r1 = (int)fminf(fmaxf(y0f + 1.0f, 0.0f), (float)(FH - 1));
        float omwy = 1.0f - wy;

        if (active) {
            int bT = (r0 * FW) * (FC / 4) + sq;
            int bB = (r1 * FW) * (FC / 4) + sq;
            f32x4 a = fq[bT + x0 * (FC / 4)];
            f32x4 b = fq[bT + x1 * (FC / 4)];
            f32x4 c = fq[bB + x0 * (FC / 4)];
            f32x4 d = fq[bB + x1 * (FC / 4)];

            // reference ordering: top = a*(1-wx)+b*wx; bot = c*(1-wx)+d*wx;
            // out = top*(1-wy) + bot*wy
            f32x4 res = (a * omwx + b * wx) * omwy + (c * omwx + d * wx) * wy;

            __builtin_nontemporal_store(res, ob + (i * PW + j) * (FC / 4));
        }
    }
}

extern "C" void kernel_launch(void* const* d_in, const int* in_sizes, int n_in,
                              void* d_out, int out_size, void* d_ws, size_t ws_size,
                              hipStream_t stream) {
    const float* feat     = (const float*)d_in[0];
    const float* rois     = (const float*)d_in[1];
    const int*   img_size = (const int*)d_in[2];
    float* out = (float*)d_out;

    int n_rois = in_sizes[1] / 4;            // 512
    int grid   = n_rois * NSL;               // 8192 blocks

    roi_crop_resize_kernel<<<grid, 256, 0, stream>>>(feat, rois, img_size, out);
}